// Round 1
// baseline (4685.469 us; speedup 1.0000x reference)
//
#include <hip/hip_runtime.h>

// Problem constants (fixed by the reference file).
#define N_NODES 65536
#define D_FEAT  256
// out layout (float32): [0,N) node_ids | [N, N+N*D) mean messages | [N+N*D, N+N*D+N) ts max

__global__ void init_kernel(float* __restrict__ out, unsigned int* __restrict__ counts) {
    const long long total = (long long)N_NODES * D_FEAT;
    long long i = (long long)blockIdx.x * blockDim.x + threadIdx.x;
    if (i >= total) return;
    float* sums = out + N_NODES;
    float* ts   = out + N_NODES + (long long)N_NODES * D_FEAT;
    sums[i] = 0.0f;
    if (i < N_NODES) {
        out[i]    = (float)i;   // node_ids as float values
        ts[i]     = 0.0f;       // timestamps >= 0, so 0 is a safe identity for max
        counts[i] = 0u;
    }
}

__global__ void scatter_kernel(const float4* __restrict__ msg4,   // [E*64] (E rows of 64 float4)
                               const float* __restrict__ timestamp,
                               const int* __restrict__ node_index,
                               float* __restrict__ out,
                               unsigned int* __restrict__ counts,
                               int E) {
    const int wave = (blockIdx.x << 2) + (threadIdx.x >> 6);  // one wave per event
    const int lane = threadIdx.x & 63;
    if (wave >= E) return;

    const int idx = node_index[wave];   // same address all lanes -> broadcast

    if (lane == 0) {
        atomicAdd(&counts[idx], 1u);
        // positive IEEE floats compare identically as uints
        unsigned int tb = __float_as_uint(timestamp[wave]);
        atomicMax((unsigned int*)(out + N_NODES + (size_t)N_NODES * D_FEAT) + idx, tb);
    }

    // coalesced 1KB row read: lane i -> float4 at column 4*i
    float4 m = msg4[(size_t)wave * 64 + lane];
    float* dst = out + N_NODES + (size_t)idx * D_FEAT + lane * 4;
    unsafeAtomicAdd(dst + 0, m.x);
    unsafeAtomicAdd(dst + 1, m.y);
    unsafeAtomicAdd(dst + 2, m.z);
    unsafeAtomicAdd(dst + 3, m.w);
}

__global__ void finalize_kernel(float* __restrict__ out, const unsigned int* __restrict__ counts) {
    // one thread per float4 of the sums region
    size_t i = (size_t)blockIdx.x * blockDim.x + threadIdx.x;   // [0, N*D/4)
    size_t n = i >> 6;                                           // 64 float4 per node row
    float c = (float)counts[n];
    float inv = (c > 0.0f) ? (1.0f / c) : 0.0f;
    float4* sums4 = (float4*)(out + N_NODES);
    float4 v = sums4[i];
    v.x *= inv; v.y *= inv; v.z *= inv; v.w *= inv;
    sums4[i] = v;
}

extern "C" void kernel_launch(void* const* d_in, const int* in_sizes, int n_in,
                              void* d_out, int out_size, void* d_ws, size_t ws_size,
                              hipStream_t stream) {
    const float* messages  = (const float*)d_in[0];
    const float* timestamp = (const float*)d_in[1];
    const int*   node_index = (const int*)d_in[2];
    const int E = in_sizes[2];

    float* out = (float*)d_out;
    unsigned int* counts = (unsigned int*)d_ws;   // N uints of scratch

    // init: N*D threads covers everything (N*D = 16,777,216 = 65536 blocks * 256)
    init_kernel<<<65536, 256, 0, stream>>>(out, counts);
    // scatter: one wave per event, 4 waves per block
    scatter_kernel<<<(E + 3) / 4, 256, 0, stream>>>((const float4*)messages, timestamp,
                                                    node_index, out, counts, E);
    // finalize: N*D/4 float4 elements = 16384 blocks * 256
    finalize_kernel<<<16384, 256, 0, stream>>>(out, counts);
}